// Round 4
// baseline (54.316 us; speedup 1.0000x reference)
//
#include <hip/hip_runtime.h>

// RPNPooling: B=2, H=128, W=128, C=256, N=512, POOL=14
// out[q,i,j,ch], q in [0,1024), i,j in [0,14), ch in [0,256)
// Reference quirk: r-axis (feature H index) derives from roi x-coords,
// c-axis (feature W index) derives from roi y-coords. Replicated verbatim.
//
// R3 = R2 + device-side spatial ROI schedule: a 1-block bitonic sort orders
// ROIs by (batch, Morton(coarse r, coarse c)); the XCD swizzle then gives
// each XCD 128 spatially-clustered ROIs so cross-ROI patch overlap hits the
// XCD's 4 MiB L2 instead of re-pulling ~147 MB through Infinity Cache.

typedef float f32x4 __attribute__((ext_vector_type(4)));

#define NROI 1024
#define CMAX 15          // roi span is in [8,15]
#define THREADS 448      // 7 waves
#define NWG (NROI * 14)  // 14336
#define WG_PER_XCD (NWG / 8)  // 1792

__device__ __forceinline__ unsigned spread3(unsigned v) {
    v &= 7u;
    return (v & 1u) | ((v & 2u) << 1) | ((v & 4u) << 2);
}

// One block, 1024 threads: sort ROI indices by spatial key, emit permutation.
// key = (b<<6 | morton(x1>>4, y1>>4)) << 10 | q  — unique => deterministic perm.
__global__ __launch_bounds__(1024) void roi_sort_kernel(
    const int* __restrict__ roi, int* __restrict__ perm)
{
    __shared__ unsigned key[NROI];
    const int t = threadIdx.x;
    const int4 rr = ((const int4*)roi)[t];
    const int b = t >> 9;
    // r-axis (H) start = x1 = rr.y; c-axis (W) start = y1 = rr.x (reference swap)
    const unsigned m = spread3((unsigned)rr.y >> 4) | (spread3((unsigned)rr.x >> 4) << 1);
    key[t] = ((((unsigned)b << 6) | m) << 10) | (unsigned)t;
    __syncthreads();
    for (int size = 2; size <= NROI; size <<= 1) {
        for (int stride = size >> 1; stride > 0; stride >>= 1) {
            const int p = t ^ stride;
            const unsigned a  = key[t];
            const unsigned bk = key[p];
            __syncthreads();
            const bool asc = ((t & size) == 0);
            const bool keepmin = ((t < p) == asc);
            key[t] = keepmin ? min(a, bk) : max(a, bk);
            __syncthreads();
        }
    }
    perm[t] = (int)(key[t] & 1023u);
}

__global__ __launch_bounds__(THREADS) void rpn_pool_kernel(
    const float* __restrict__ feat,   // [2,128,128,256]
    const int*   __restrict__ roi,    // [1024,4] = y1,x1,y2,x2
    const int*   __restrict__ perm,   // [1024] spatial schedule
    float*       __restrict__ out)    // [1024,14,14,256]
{
    __shared__ float lds[2][CMAX][256];   // 30 KB

    // XCD-aware swizzle (bijective: NWG % 8 == 0): XCD k owns schedule slots
    // [k*128,(k+1)*128) — contiguous in sorted order => spatially clustered.
    const int d = blockIdx.x;
    const int w = (d & 7) * WG_PER_XCD + (d >> 3);
    const int g = w / 14;             // schedule slot
    const int i = w - g * 14;
    const int q = perm[g];            // actual ROI index
    const int b = q >> 9;             // q / 512

    const int4 rr = ((const int4*)roi)[q];
    const int y1 = rr.x, x1 = rr.y, y2 = rr.z, x2 = rr.w;

    const int sR = x2 - x1;           // H-extent from x coords (reference swap)
    const int sC = y2 - y1;           // W-extent from y coords

    const int pr  = i * sR;
    const int ir0 = pr / 14;
    const float fr = (float)(pr - ir0 * 14) * (1.0f / 14.0f);
    const int r0 = x1 + ir0;
    const int r1 = x1 + min(ir0 + 1, sR - 1);

    const size_t SB = (size_t)128 * 128 * 256;
    const size_t SR = (size_t)128 * 256;

    const float* base = feat + (size_t)b * SB;
    const f32x4* row0 = (const f32x4*)(base + (size_t)r0 * SR + (size_t)y1 * 256);
    const f32x4* row1 = (const f32x4*)(base + (size_t)r1 * SR + (size_t)y1 * 256);

    // Stage two contiguous row segments (sC * 1KB each) into LDS.
    const int rowElems = sC * 64;     // f32x4 count per row
    f32x4* lds4 = (f32x4*)lds;
    for (int idx = threadIdx.x; idx < rowElems; idx += THREADS)
        lds4[idx] = row0[idx];
    for (int idx = threadIdx.x; idx < rowElems; idx += THREADS)
        lds4[CMAX * 64 + idx] = row1[idx];
    __syncthreads();

    const int wave = threadIdx.x >> 6;
    const int lane = threadIdx.x & 63;
    const float wr1 = 1.0f - fr;

    for (int j = wave; j < 14; j += 7) {
        const int pc  = j * sC;
        const int ic0 = pc / 14;
        const float fc = (float)(pc - ic0 * 14) * (1.0f / 14.0f);
        const int c0 = ic0;                 // local column index in LDS
        const int c1 = min(ic0 + 1, sC - 1);
        const float wc1 = 1.0f - fc;

        const f32x4 g00 = ((const f32x4*)lds[0][c0])[lane];
        const f32x4 g01 = ((const f32x4*)lds[0][c1])[lane];
        const f32x4 g10 = ((const f32x4*)lds[1][c0])[lane];
        const f32x4 g11 = ((const f32x4*)lds[1][c1])[lane];

        f32x4 o = (g00 * wc1 + g01 * fc) * wr1 + (g10 * wc1 + g11 * fc) * fr;

        const size_t oidx = ((size_t)q * 196 + (size_t)i * 14 + j) * 64 + lane;
        __builtin_nontemporal_store(o, ((f32x4*)out) + oidx);
    }
}

extern "C" void kernel_launch(void* const* d_in, const int* in_sizes, int n_in,
                              void* d_out, int out_size, void* d_ws, size_t ws_size,
                              hipStream_t stream) {
    const float* feat = (const float*)d_in[0];
    const int*   roi  = (const int*)d_in[1];
    float* out = (float*)d_out;
    int*   perm = (int*)d_ws;

    roi_sort_kernel<<<1, 1024, 0, stream>>>(roi, perm);
    rpn_pool_kernel<<<NWG, THREADS, 0, stream>>>(feat, roi, perm, out);
}

// Round 5
// 50.923 us; speedup vs baseline: 1.0666x; 1.0666x over previous
//
#include <hip/hip_runtime.h>

// RPNPooling: B=2, H=128, W=128, C=256, N=512, POOL=14
// out[q,i,j,ch], q in [0,1024), i,j in [0,14), ch in [0,256)
// Reference quirk: r-axis (feature H index) derives from roi x-coords,
// c-axis (feature W index) derives from roi y-coords. Replicated verbatim.
//
// R4: one block per ROI, 14 waves (wave w = output column j), rolling 3-row
// LDS window. Each i-step stages at most ONE new feature row (rows advance
// monotonically, step<=1 since sR<=15); the row load issues BEFORE the
// current step's compute so HBM latency hides under it (T14). Reads drop
// from 330 MB (R2: 2 rows per (q,i) block, 2.4x duplicated) to the distinct
// patch only (~135 MB). Writes 205 MB nontemporal.

typedef float f32x4 __attribute__((ext_vector_type(4)));

#define NROI 1024
#define CMAX 15          // roi span is in [8,15]
#define THREADS 896      // 14 waves

__global__ __launch_bounds__(THREADS) void rpn_pool_kernel(
    const float* __restrict__ feat,   // [2,128,128,256]
    const int*   __restrict__ roi,    // [1024,4] = y1,x1,y2,x2
    float*       __restrict__ out)    // [1024,14,14,256]
{
    __shared__ f32x4 lds[3][CMAX * 64];   // 3 rolling rows, 45 KB

    // XCD chunking (bijective, 1024 % 8 == 0)
    const int d = blockIdx.x;
    const int q = (d & 7) * (NROI / 8) + (d >> 3);
    const int b = q >> 9;

    const int4 rr = ((const int4*)roi)[q];
    const int y1 = rr.x, x1 = rr.y, y2 = rr.z, x2 = rr.w;
    const int sR = x2 - x1;           // H-extent from x coords (reference swap)
    const int sC = y2 - y1;           // W-extent from y coords
    const int rowElems = sC * 64;     // f32x4 per staged row (512..960)

    const size_t SB = (size_t)128 * 128 * 256;
    const size_t SR = (size_t)128 * 256;
    // local row k (k = global_row - x1) lives at base + k*SR
    const float* base = feat + (size_t)b * SB + (size_t)x1 * SR + (size_t)y1 * 256;

    const int t    = threadIdx.x;
    const int wave = t >> 6;
    const int lane = t & 63;

    // Prologue: stage local rows 0 and 1 (sR >= 8 so both exist).
    {
        const f32x4* r0p = (const f32x4*)base;
        const f32x4* r1p = (const f32x4*)(base + SR);
        if (t < rowElems)           { lds[0][t] = r0p[t];  lds[1][t] = r1p[t]; }
        if (t + THREADS < rowElems) { lds[0][t + THREADS] = r0p[t + THREADS];
                                      lds[1][t + THREADS] = r1p[t + THREADS]; }
    }
    __syncthreads();
    int hi = 1;   // highest local row staged

    // Per-wave column constants (wave w owns j = w, w in [0,14))
    const int j   = wave;
    const int pc  = j * sC;
    const int ic0 = pc / 14;
    const float fc  = (float)(pc - ic0 * 14) * (1.0f / 14.0f);
    const float wc1 = 1.0f - fc;
    const int c0 = ic0 * 64 + lane;                 // f32x4 index in a row slot
    const int c1 = min(ic0 + 1, sC - 1) * 64 + lane;

    for (int i = 0; i < 14; ++i) {
        const int pr  = i * sR;
        const int ir0 = pr / 14;
        const float fr = (float)(pr - ir0 * 14) * (1.0f / 14.0f);
        const int rA = ir0;                     // rows needed this step
        const int rB = min(ir0 + 1, sR - 1);    // (staged by end of step i-1)

        // Issue next row's loads BEFORE compute (latency hides under it).
        // Rows in use are rA, rB <= hi; new row nextHi <= rA+2, its slot holds
        // old row nextHi-3 <= rA-1 which no wave reads this step -> WAR-safe.
        int nextHi = hi;
        f32x4 v0, v1;
        bool ld0 = false, ld1 = false;
        if (i < 13) {
            const int need = min((i + 1) * sR / 14 + 1, sR - 1);
            if (need > hi) {
                nextHi = hi + 1;
                const f32x4* rp = (const f32x4*)(base + (size_t)nextHi * SR);
                if (t < rowElems)           { v0 = rp[t];           ld0 = true; }
                if (t + THREADS < rowElems) { v1 = rp[t + THREADS]; ld1 = true; }
            }
        }

        // Compute this step's cell from staged rows.
        const int sA = rA % 3, sB = rB % 3;
        const f32x4 g00 = lds[sA][c0];
        const f32x4 g01 = lds[sA][c1];
        const f32x4 g10 = lds[sB][c0];
        const f32x4 g11 = lds[sB][c1];
        f32x4 o = (g00 * wc1 + g01 * fc) * (1.0f - fr) + (g10 * wc1 + g11 * fc) * fr;
        const size_t oidx = ((size_t)q * 196 + (size_t)i * 14 + j) * 64 + lane;
        __builtin_nontemporal_store(o, ((f32x4*)out) + oidx);

        // Land the staged row, advance window, one barrier per step.
        if (nextHi != hi) {
            const int slot = nextHi % 3;
            if (ld0) lds[slot][t] = v0;
            if (ld1) lds[slot][t + THREADS] = v1;
            hi = nextHi;
        }
        __syncthreads();
    }
}

extern "C" void kernel_launch(void* const* d_in, const int* in_sizes, int n_in,
                              void* d_out, int out_size, void* d_ws, size_t ws_size,
                              hipStream_t stream) {
    const float* feat = (const float*)d_in[0];
    const int*   roi  = (const int*)d_in[1];
    float* out = (float*)d_out;

    rpn_pool_kernel<<<NROI, THREADS, 0, stream>>>(feat, roi, out);
}